// Round 3
// baseline (177.962 us; speedup 1.0000x reference)
//
#include <hip/hip_runtime.h>

typedef unsigned short us;
typedef __attribute__((ext_vector_type(8))) short short8;
typedef __attribute__((ext_vector_type(4))) float f32x4;

__device__ __forceinline__ us f2bf(float f) {
  unsigned int u = __builtin_bit_cast(unsigned int, f);
  u += 0x7fffu + ((u >> 16) & 1u);
  return (us)(u >> 16);
}

// 16B-wide async global->LDS DMA. LDS dest = wave-uniform base + lane*16.
__device__ __forceinline__ void gload_lds16(const void* g, void* l) {
  __builtin_amdgcn_global_load_lds(
      (const __attribute__((address_space(1))) void*)g,
      (__attribute__((address_space(3))) void*)l, 16, 0, 0);
}

// ---- prep: token cast (4096 blks) + Wt transpose (256) + entity GEMM f32 (128) ----
__global__ __launch_bounds__(256) void prep_kernel(
    const float* __restrict__ token, us* __restrict__ tokb,
    const float* __restrict__ Wt, us* __restrict__ WtT,
    const float* __restrict__ entity, const float* __restrict__ We,
    const float* __restrict__ be, float* __restrict__ ews) {
  __shared__ float tile[64][65];
  __shared__ float4 part[16][8];
  const int bid = blockIdx.x, tid = threadIdx.x;
  if (bid < 4096) {  // token f32 -> bf16
    int q = bid * 256 + tid;
    float4 v = ((const float4*)token)[q];
    ushort4 o;
    o.x = f2bf(v.x); o.y = f2bf(v.y); o.z = f2bf(v.z); o.w = f2bf(v.w);
    ((ushort4*)tokb)[q] = o;
  } else if (bid < 4352) {  // Wt[k][n] -> WtT[n][k] bf16
    int tb = bid - 4096;
    int bx = (tb & 15) << 6, by = ((tb >> 4) & 15) << 6;
    int r0 = tid >> 4, c0 = (tid & 15) << 2;
#pragma unroll
    for (int p = 0; p < 4; ++p) {
      int r = p * 16 + r0;
      float4 v = *(const float4*)&Wt[(size_t)(by + r) * 1024 + bx + c0];
      tile[r][c0] = v.x; tile[r][c0 + 1] = v.y;
      tile[r][c0 + 2] = v.z; tile[r][c0 + 3] = v.w;
    }
    __syncthreads();
#pragma unroll
    for (int p = 0; p < 4; ++p) {
      int r = p * 16 + r0;
      ushort4 o;
      o.x = f2bf(tile[c0 + 0][r]); o.y = f2bf(tile[c0 + 1][r]);
      o.z = f2bf(tile[c0 + 2][r]); o.w = f2bf(tile[c0 + 3][r]);
      *(ushort4*)&WtT[(size_t)(bx + r) * 1024 + by + c0] = o;
    }
  } else {  // entity branch: ews[b,r,n] = entity[b,r,:]@We[:,n] + be[n]  (f32 VALU)
    int eb = bid - 4352;            // 0..127
    int b = eb >> 5, n0 = (eb & 31) << 5;
    int c4 = tid & 7, rr = (tid >> 3) & 15, kh = tid >> 7;
    const float* wrow = We + (size_t)(kh * 512) * 1024 + n0 + (c4 << 2);
    const float* ent = entity + (size_t)(((b << 4) + rr) << 10) + kh * 512;
    f32x4 a = {0.f, 0.f, 0.f, 0.f};
#pragma unroll 8
    for (int k = 0; k < 512; ++k) {
      float4 wv = *(const float4*)&wrow[(size_t)k * 1024];
      float evv = ent[k];
      a[0] = fmaf(wv.x, evv, a[0]); a[1] = fmaf(wv.y, evv, a[1]);
      a[2] = fmaf(wv.z, evv, a[2]); a[3] = fmaf(wv.w, evv, a[3]);
    }
    if (kh) part[rr][c4] = (float4){a[0], a[1], a[2], a[3]};
    __syncthreads();
    if (!kh) {
      float4 p2 = part[rr][c4];
      const float* bev = &be[n0 + (c4 << 2)];
      float4 o;
      o.x = a[0] + p2.x + bev[0]; o.y = a[1] + p2.y + bev[1];
      o.z = a[2] + p2.z + bev[2]; o.w = a[3] + p2.w + bev[3];
      *(float4*)&ews[(size_t)(((b << 4) + rr) << 10) + n0 + (c4 << 2)] = o;
    }
  }
}

// ---- main: transposed token GEMM (C[h,t]) + fused relu-dot epilogue ----
// grid (8 h-tiles, 32 t-tiles). Manual double-buffer pipeline:
// raw s_barrier + s_waitcnt vmcnt(4), prefetch depth 2.
__global__ __launch_bounds__(256) void main_kernel(
    const us* __restrict__ tokb, const us* __restrict__ WtT,
    const float* __restrict__ ews, const float* __restrict__ bt,
    const float* __restrict__ wp, float* __restrict__ partial) {
  __shared__ __attribute__((aligned(16))) us Ws[2][4096];   // [buf][128 rows x 32 k]
  __shared__ __attribute__((aligned(16))) us Ts[2][4096];
  __shared__ __attribute__((aligned(16))) float eL[16][132];
  __shared__ __attribute__((aligned(16))) float btL[128];
  __shared__ __attribute__((aligned(16))) float wpL[128];
  __shared__ float pp[2][128][17];
  const int tid = threadIdx.x;
  const int mh = blockIdx.x, tt = blockIdx.y;
  const int h0 = mh << 7, b = tt >> 3;
  // phase 1: epilogue operands -> LDS (drained before DMA issue)
#pragma unroll
  for (int p = 0; p < 2; ++p) {
    int q = (p << 8) + tid;
    int er = q >> 5, ec = (q & 31) << 2;
    float4 v = *(const float4*)&ews[(size_t)(((b << 4) + er) << 10) + h0 + ec];
    *(float4*)&eL[er][ec] = v;
  }
  if (tid < 128) btL[tid] = bt[h0 + tid];
  else wpL[tid - 128] = wp[h0 + tid - 128];
  asm volatile("" ::: "memory");
  // staging pointers: 4 DMA per wave per tile (As 64B/row layout)
  const int row1 = tid >> 2, kc = (tid & 3) << 3;
  const us* wP = WtT + (size_t)(h0 + row1) * 1024 + kc;
  const us* tP = tokb + (size_t)((tt << 7) + row1) * 1024 + kc;
  const int w = tid >> 6;
  us* w0 = &Ws[0][w * 512]; us* w1 = &Ws[1][w * 512];
  us* t0 = &Ts[0][w * 512]; us* t1 = &Ts[1][w * 512];
  // prologue: tile0 -> buf0, tile1 -> buf1  (8 outstanding)
  gload_lds16(wP, w0); gload_lds16(wP + 65536, w0 + 2048);
  gload_lds16(tP, t0); gload_lds16(tP + 65536, t0 + 2048);
  gload_lds16(wP + 32, w1); gload_lds16(wP + 65536 + 32, w1 + 2048);
  gload_lds16(tP + 32, t1); gload_lds16(tP + 65536 + 32, t1 + 2048);
  const int lane = tid & 63, wm = (tid >> 7) & 1, wn = (tid >> 6) & 1;
  const int l16 = lane & 15, oct = lane >> 4, ko = oct << 3;
  int wfo[4], tfo[4];
#pragma unroll
  for (int i = 0; i < 4; ++i) {
    wfo[i] = (((wm << 6) + (i << 4) + l16) << 5) + ko;
    tfo[i] = (((wn << 6) + (i << 4) + l16) << 5) + ko;
  }
  f32x4 acc[4][4] = {};
  for (int kt = 0; kt < 32; ++kt) {
    const us* Wb = Ws[kt & 1];
    const us* Tb = Ts[kt & 1];
    __builtin_amdgcn_s_waitcnt(0x0f74);  // vmcnt(4): oldest tile landed
    __builtin_amdgcn_s_barrier();
    asm volatile("" ::: "memory");
    short8 af[4], bfr[4];
#pragma unroll
    for (int i = 0; i < 4; ++i) af[i] = *(const short8*)&Wb[wfo[i]];
#pragma unroll
    for (int j = 0; j < 4; ++j) bfr[j] = *(const short8*)&Tb[tfo[j]];
#pragma unroll
    for (int i = 0; i < 4; ++i)
#pragma unroll
      for (int j = 0; j < 4; ++j)
        acc[i][j] = __builtin_amdgcn_mfma_f32_16x16x32_bf16(af[i], bfr[j], acc[i][j], 0, 0, 0);
    asm volatile("" ::: "memory");
    __builtin_amdgcn_s_barrier();
    // prefetch tile kt+2 into buf kt&1 (clamped dummy for last two iters)
    int nk = kt + 2; if (nk > 31) nk = 30;
    int ko2 = nk << 5;
    us* dw = (kt & 1) ? w1 : w0;
    us* dt = (kt & 1) ? t1 : t0;
    gload_lds16(wP + ko2, dw); gload_lds16(wP + 65536 + ko2, dw + 2048);
    gload_lds16(tP + ko2, dt); gload_lds16(tP + 65536 + ko2, dt + 2048);
  }
  // ---- fused epilogue: per e, p[t] = sum_h relu(acc + bt + e) * Wp ----
  f32x4 btq[4], wpq[4];
#pragma unroll
  for (int i = 0; i < 4; ++i) {
    int hb = (wm << 6) + (i << 4) + (oct << 2);
    btq[i] = *(const f32x4*)&btL[hb];
    wpq[i] = *(const f32x4*)&wpL[hb];
  }
#pragma unroll
  for (int i = 0; i < 4; ++i)
#pragma unroll
    for (int j = 0; j < 4; ++j) acc[i][j] += btq[i];
#pragma unroll
  for (int e = 0; e < 16; ++e) {
    f32x4 ev[4];
#pragma unroll
    for (int i = 0; i < 4; ++i)
      ev[i] = *(const f32x4*)&eL[e][(wm << 6) + (i << 4) + (oct << 2)];
    float pj[4] = {0.f, 0.f, 0.f, 0.f};
#pragma unroll
    for (int j = 0; j < 4; ++j)
#pragma unroll
      for (int i = 0; i < 4; ++i)
#pragma unroll
        for (int r = 0; r < 4; ++r)
          pj[j] = fmaf(fmaxf(acc[i][j][r] + ev[i][r], 0.f), wpq[i][r], pj[j]);
#pragma unroll
    for (int j = 0; j < 4; ++j) {
      pj[j] += __shfl_xor(pj[j], 16, 64);
      pj[j] += __shfl_xor(pj[j], 32, 64);
    }
    if (oct == 0) {
#pragma unroll
      for (int j = 0; j < 4; ++j) pp[wm][(wn << 6) + (j << 4) + l16][e] = pj[j];
    }
  }
  __syncthreads();
#pragma unroll
  for (int q = 0; q < 8; ++q) {
    int flat = (q << 8) + tid;
    int e = flat >> 7, tl = flat & 127;
    float v = pp[0][tl][e] + pp[1][tl][e];
    partial[((size_t)mh << 16) + (size_t)((((b << 4) + e) << 10) + ((tt & 7) << 7) + tl)] = v;
  }
}

// ---- finalize: sum 8 h-tile partials + bp, mask, sigmoid ----
__global__ __launch_bounds__(256) void finalize_kernel(
    const float* __restrict__ partial, const float* __restrict__ bp,
    const int* __restrict__ mask, float* __restrict__ out) {
  int idx = blockIdx.x * 256 + threadIdx.x;  // (b*16+e)*1024 + t
  float s = 0.f;
#pragma unroll
  for (int mh = 0; mh < 8; ++mh) s += partial[((size_t)mh << 16) + idx];
  float cls = s + bp[0];
  int b = idx >> 14, t = idx & 1023;
  if (mask[(b << 10) + t] == 0) cls = -10000.0f;
  float p = 1.0f / (1.0f + __expf(-cls));
  out[idx] = cls;
  out[65536 + idx] = p;
}

extern "C" void kernel_launch(void* const* d_in, const int* in_sizes, int n_in,
                              void* d_out, int out_size, void* d_ws, size_t ws_size,
                              hipStream_t stream) {
  const float* token = (const float*)d_in[0];
  const float* entity = (const float*)d_in[1];
  const int* mask = (const int*)d_in[2];
  const float* Wt = (const float*)d_in[3];
  const float* bt = (const float*)d_in[4];
  const float* We = (const float*)d_in[5];
  const float* be = (const float*)d_in[6];
  const float* Wp = (const float*)d_in[7];
  const float* bp = (const float*)d_in[8];
  float* out = (float*)d_out;

  char* ws = (char*)d_ws;
  us* tokb = (us*)ws;                                   // 8 MB
  us* WtT = tokb + (size_t)4096 * 1024;                 // 2 MB
  float* ews = (float*)(WtT + (size_t)1024 * 1024);     // 256 KB (entity acts, f32)
  float* partial = ews + (size_t)64 * 1024;             // 2 MB  [8][4*16*1024]

  prep_kernel<<<4480, 256, 0, stream>>>(token, tokb, Wt, WtT, entity, We, be, ews);
  main_kernel<<<dim3(8, 32), 256, 0, stream>>>(tokb, WtT, ews, bt, Wp, partial);
  finalize_kernel<<<256, 256, 0, stream>>>(partial, bp, mask, out);
}

// Round 4
// 124.061 us; speedup vs baseline: 1.4345x; 1.4345x over previous
//
#include <hip/hip_runtime.h>

typedef unsigned short us;
typedef __attribute__((ext_vector_type(8))) short short8;
typedef __attribute__((ext_vector_type(4))) float f32x4;

__device__ __forceinline__ us f2bf(float f) {
  unsigned int u = __builtin_bit_cast(unsigned int, f);
  u += 0x7fffu + ((u >> 16) & 1u);
  return (us)(u >> 16);
}

// 16B-wide async global->LDS DMA. LDS dest = wave-uniform base + lane*16.
__device__ __forceinline__ void gload_lds16(const void* g, void* l) {
  __builtin_amdgcn_global_load_lds(
      (const __attribute__((address_space(1))) void*)g,
      (__attribute__((address_space(3))) void*)l, 16, 0, 0);
}

// ---- prep: token cast (4096) + Wt transpose (256) + entity k-split GEMM (256) ----
// entity partials: epart[kc][b*16+r][n], 8 k-chunks of 128, f32.
__global__ __launch_bounds__(256) void prep_kernel(
    const float* __restrict__ token, us* __restrict__ tokb,
    const float* __restrict__ Wt, us* __restrict__ WtT,
    const float* __restrict__ entity, const float* __restrict__ We,
    float* __restrict__ epart) {
  __shared__ float tile[64][65];
  __shared__ float eS[16][128];
  const int bid = blockIdx.x, tid = threadIdx.x;
  if (bid < 4096) {  // token f32 -> bf16
    int q = bid * 256 + tid;
    float4 v = ((const float4*)token)[q];
    ushort4 o;
    o.x = f2bf(v.x); o.y = f2bf(v.y); o.z = f2bf(v.z); o.w = f2bf(v.w);
    ((ushort4*)tokb)[q] = o;
  } else if (bid < 4352) {  // Wt[k][n] -> WtT[n][k] bf16
    int tb = bid - 4096;
    int bx = (tb & 15) << 6, by = ((tb >> 4) & 15) << 6;
    int r0 = tid >> 4, c0 = (tid & 15) << 2;
#pragma unroll
    for (int p = 0; p < 4; ++p) {
      int r = p * 16 + r0;
      float4 v = *(const float4*)&Wt[(size_t)(by + r) * 1024 + bx + c0];
      tile[r][c0] = v.x; tile[r][c0 + 1] = v.y;
      tile[r][c0 + 2] = v.z; tile[r][c0 + 3] = v.w;
    }
    __syncthreads();
#pragma unroll
    for (int p = 0; p < 4; ++p) {
      int r = p * 16 + r0;
      ushort4 o;
      o.x = f2bf(tile[c0 + 0][r]); o.y = f2bf(tile[c0 + 1][r]);
      o.z = f2bf(tile[c0 + 2][r]); o.w = f2bf(tile[c0 + 3][r]);
      *(ushort4*)&WtT[(size_t)(bx + r) * 1024 + by + c0] = o;
    }
  } else {  // entity k-split partial GEMM, coalesced We reads
    int eb = bid - 4352;                 // 0..255
    int kc = eb & 7, nt = (eb >> 3) & 7, b = eb >> 6;
    int k0 = kc << 7, n0 = nt << 7;
    // stage entity[b, 0..15, k0..k0+127] -> LDS (broadcast-read later)
#pragma unroll
    for (int p = 0; p < 2; ++p) {
      int idx = (p << 8) + tid;          // 0..511 float4 slots
      int r = idx >> 5, kk = (idx & 31) << 2;
      *(float4*)&eS[r][kk] = *(const float4*)&entity[(size_t)(((b << 4) + r) << 10) + k0 + kk];
    }
    __syncthreads();
    const int col = tid & 127, rh = tid >> 7;   // rh: rows 0..7 or 8..15
    const float* wP = We + ((size_t)k0 << 10) + n0 + col;
    float acc[8] = {0.f, 0.f, 0.f, 0.f, 0.f, 0.f, 0.f, 0.f};
#pragma unroll 8
    for (int k = 0; k < 128; ++k) {
      float wv = wP[(size_t)k << 10];    // lanes span n: coalesced
#pragma unroll
      for (int r = 0; r < 8; ++r)
        acc[r] = fmaf(wv, eS[(rh << 3) + r][k], acc[r]);  // LDS broadcast: free
    }
    float* op = epart + (((size_t)((kc << 6) + (b << 4) + (rh << 3))) << 10) + n0 + col;
#pragma unroll
    for (int r = 0; r < 8; ++r) op[(size_t)r << 10] = acc[r];
  }
}

// ---- main: transposed token GEMM (C[h,t]) + fused relu-dot epilogue ----
// grid (8 h-tiles, 32 t-tiles). m97-style 2-barrier K-loop (proven).
__global__ __launch_bounds__(256) void main_kernel(
    const us* __restrict__ tokb, const us* __restrict__ WtT,
    const float* __restrict__ epart, const float* __restrict__ be,
    const float* __restrict__ bt, const float* __restrict__ wp,
    float* __restrict__ partial) {
  __shared__ __attribute__((aligned(16))) us Ws[4096];   // 128 rows x 32 k
  __shared__ __attribute__((aligned(16))) us Ts[4096];
  __shared__ __attribute__((aligned(16))) float eL[16][132];
  __shared__ __attribute__((aligned(16))) float btL[128];
  __shared__ __attribute__((aligned(16))) float wpL[128];
  __shared__ float pp[2][128][17];
  const int tid = threadIdx.x;
  const int mh = blockIdx.x, tt = blockIdx.y;
  const int h0 = mh << 7, b = tt >> 3;
  // phase 1: entity activation = sum of 8 k-partials + be -> eL; bt, wp -> LDS
#pragma unroll
  for (int p = 0; p < 2; ++p) {
    int q = (p << 8) + tid;
    int er = q >> 5, ec = (q & 31) << 2;
    f32x4 s = *(const f32x4*)&be[h0 + ec];
#pragma unroll
    for (int kc = 0; kc < 8; ++kc)
      s += *(const f32x4*)&epart[(((size_t)((kc << 6) + (b << 4) + er)) << 10) + h0 + ec];
    *(f32x4*)&eL[er][ec] = s;
  }
  if (tid < 128) btL[tid] = bt[h0 + tid];
  else wpL[tid - 128] = wp[h0 + tid - 128];
  // staging pointers: 4 DMA per wave per K-tile
  const int row1 = tid >> 2, kc4 = (tid & 3) << 3;
  const us* wP = WtT + (size_t)(h0 + row1) * 1024 + kc4;
  const us* tP = tokb + (size_t)((tt << 7) + row1) * 1024 + kc4;
  const int w = tid >> 6;
  us* wL = &Ws[w * 512];
  us* tL = &Ts[w * 512];
  const int lane = tid & 63, wm = (tid >> 7) & 1, wn = (tid >> 6) & 1;
  const int l16 = lane & 15, oct = lane >> 4, ko = oct << 3;
  int wfo[4], tfo[4];
#pragma unroll
  for (int i = 0; i < 4; ++i) {
    wfo[i] = (((wm << 6) + (i << 4) + l16) << 5) + ko;
    tfo[i] = (((wn << 6) + (i << 4) + l16) << 5) + ko;
  }
  f32x4 acc[4][4] = {};
  for (int kt = 0; kt < 32; ++kt) {
    const int ko2 = kt << 5;
    __syncthreads();
    gload_lds16(wP + ko2, wL); gload_lds16(wP + 65536 + ko2, wL + 2048);
    gload_lds16(tP + ko2, tL); gload_lds16(tP + 65536 + ko2, tL + 2048);
    __syncthreads();
    short8 af[4], bfr[4];
#pragma unroll
    for (int i = 0; i < 4; ++i) af[i] = *(const short8*)&Ws[wfo[i]];
#pragma unroll
    for (int j = 0; j < 4; ++j) bfr[j] = *(const short8*)&Ts[tfo[j]];
#pragma unroll
    for (int i = 0; i < 4; ++i)
#pragma unroll
      for (int j = 0; j < 4; ++j)
        acc[i][j] = __builtin_amdgcn_mfma_f32_16x16x32_bf16(af[i], bfr[j], acc[i][j], 0, 0, 0);
  }
  // ---- fused epilogue: per e, p[t] = sum_h relu(acc + bt + e) * Wp ----
  f32x4 btq[4], wpq[4];
#pragma unroll
  for (int i = 0; i < 4; ++i) {
    int hb = (wm << 6) + (i << 4) + (oct << 2);
    btq[i] = *(const f32x4*)&btL[hb];
    wpq[i] = *(const f32x4*)&wpL[hb];
  }
#pragma unroll
  for (int i = 0; i < 4; ++i)
#pragma unroll
    for (int j = 0; j < 4; ++j) acc[i][j] += btq[i];
#pragma unroll
  for (int e = 0; e < 16; ++e) {
    f32x4 ev[4];
#pragma unroll
    for (int i = 0; i < 4; ++i)
      ev[i] = *(const f32x4*)&eL[e][(wm << 6) + (i << 4) + (oct << 2)];
    float pj[4] = {0.f, 0.f, 0.f, 0.f};
#pragma unroll
    for (int j = 0; j < 4; ++j)
#pragma unroll
      for (int i = 0; i < 4; ++i)
#pragma unroll
        for (int r = 0; r < 4; ++r)
          pj[j] = fmaf(fmaxf(acc[i][j][r] + ev[i][r], 0.f), wpq[i][r], pj[j]);
#pragma unroll
    for (int j = 0; j < 4; ++j) {
      pj[j] += __shfl_xor(pj[j], 16, 64);
      pj[j] += __shfl_xor(pj[j], 32, 64);
    }
    if (oct == 0) {
#pragma unroll
      for (int j = 0; j < 4; ++j) pp[wm][(wn << 6) + (j << 4) + l16][e] = pj[j];
    }
  }
  __syncthreads();
#pragma unroll
  for (int q = 0; q < 8; ++q) {
    int flat = (q << 8) + tid;
    int e = flat >> 7, tl = flat & 127;
    float v = pp[0][tl][e] + pp[1][tl][e];
    partial[((size_t)mh << 16) + (size_t)((((b << 4) + e) << 10) + ((tt & 7) << 7) + tl)] = v;
  }
}

// ---- finalize: sum 8 h-tile partials + bp, mask, sigmoid ----
__global__ __launch_bounds__(256) void finalize_kernel(
    const float* __restrict__ partial, const float* __restrict__ bp,
    const int* __restrict__ mask, float* __restrict__ out) {
  int idx = blockIdx.x * 256 + threadIdx.x;  // (b*16+e)*1024 + t
  float s = 0.f;
#pragma unroll
  for (int mh = 0; mh < 8; ++mh) s += partial[((size_t)mh << 16) + idx];
  float cls = s + bp[0];
  int b = idx >> 14, t = idx & 1023;
  if (mask[(b << 10) + t] == 0) cls = -10000.0f;
  float p = 1.0f / (1.0f + __expf(-cls));
  out[idx] = cls;
  out[65536 + idx] = p;
}

extern "C" void kernel_launch(void* const* d_in, const int* in_sizes, int n_in,
                              void* d_out, int out_size, void* d_ws, size_t ws_size,
                              hipStream_t stream) {
  const float* token = (const float*)d_in[0];
  const float* entity = (const float*)d_in[1];
  const int* mask = (const int*)d_in[2];
  const float* Wt = (const float*)d_in[3];
  const float* bt = (const float*)d_in[4];
  const float* We = (const float*)d_in[5];
  const float* be = (const float*)d_in[6];
  const float* Wp = (const float*)d_in[7];
  const float* bp = (const float*)d_in[8];
  float* out = (float*)d_out;

  char* ws = (char*)d_ws;
  us* tokb = (us*)ws;                                   // 8 MB
  us* WtT = tokb + (size_t)4096 * 1024;                 // 2 MB
  float* epart = (float*)(WtT + (size_t)1024 * 1024);   // 2 MB [8][64][1024]
  float* partial = epart + (size_t)8 * 64 * 1024;       // 2 MB [8][4*16*1024]

  prep_kernel<<<4608, 256, 0, stream>>>(token, tokb, Wt, WtT, entity, We, epart);
  main_kernel<<<dim3(8, 32), 256, 0, stream>>>(tokb, WtT, epart, be, bt, Wp, partial);
  finalize_kernel<<<256, 256, 0, stream>>>(partial, bp, mask, out);
}

// Round 5
// 113.950 us; speedup vs baseline: 1.5617x; 1.0887x over previous
//
#include <hip/hip_runtime.h>

typedef unsigned short us;
typedef __attribute__((ext_vector_type(8))) short short8;
typedef __attribute__((ext_vector_type(4))) float f32x4;

__device__ __forceinline__ us f2bf(float f) {
  unsigned int u = __builtin_bit_cast(unsigned int, f);
  u += 0x7fffu + ((u >> 16) & 1u);
  return (us)(u >> 16);
}

// 16B-wide async global->LDS DMA. LDS dest = wave-uniform base + lane*16.
__device__ __forceinline__ void gload_lds16(const void* g, void* l) {
  __builtin_amdgcn_global_load_lds(
      (const __attribute__((address_space(1))) void*)g,
      (__attribute__((address_space(3))) void*)l, 16, 0, 0);
}

// ---- prep: entity k-split GEMM (256, first: overlaps latency with cast BW)
//           + token cast (4096) + Wt transpose (256) ----
__global__ __launch_bounds__(256) void prep_kernel(
    const float* __restrict__ token, us* __restrict__ tokb,
    const float* __restrict__ Wt, us* __restrict__ WtT,
    const float* __restrict__ entity, const float* __restrict__ We,
    float* __restrict__ epart) {
  __shared__ float tile[64][65];
  __shared__ float eS[16][128];
  const int bid = blockIdx.x, tid = threadIdx.x;
  if (bid < 256) {  // entity k-split partial GEMM, coalesced We reads
    int kc = bid & 7, nt = (bid >> 3) & 7, b = bid >> 6;
    int k0 = kc << 7, n0 = nt << 7;
#pragma unroll
    for (int p = 0; p < 2; ++p) {
      int idx = (p << 8) + tid;
      int r = idx >> 5, kk = (idx & 31) << 2;
      *(float4*)&eS[r][kk] = *(const float4*)&entity[(size_t)(((b << 4) + r) << 10) + k0 + kk];
    }
    __syncthreads();
    const int col = tid & 127, rh = tid >> 7;
    const float* wP = We + ((size_t)k0 << 10) + n0 + col;
    float acc[8] = {0.f, 0.f, 0.f, 0.f, 0.f, 0.f, 0.f, 0.f};
#pragma unroll 8
    for (int k = 0; k < 128; ++k) {
      float wv = wP[(size_t)k << 10];
#pragma unroll
      for (int r = 0; r < 8; ++r)
        acc[r] = fmaf(wv, eS[(rh << 3) + r][k], acc[r]);
    }
    float* op = epart + (((size_t)((kc << 6) + (b << 4) + (rh << 3))) << 10) + n0 + col;
#pragma unroll
    for (int r = 0; r < 8; ++r) op[(size_t)r << 10] = acc[r];
  } else if (bid < 4352) {  // token f32 -> bf16
    int q = (bid - 256) * 256 + tid;
    float4 v = ((const float4*)token)[q];
    ushort4 o;
    o.x = f2bf(v.x); o.y = f2bf(v.y); o.z = f2bf(v.z); o.w = f2bf(v.w);
    ((ushort4*)tokb)[q] = o;
  } else {  // Wt[k][n] -> WtT[n][k] bf16
    int tb = bid - 4352;
    int bx = (tb & 15) << 6, by = ((tb >> 4) & 15) << 6;
    int r0 = tid >> 4, c0 = (tid & 15) << 2;
#pragma unroll
    for (int p = 0; p < 4; ++p) {
      int r = p * 16 + r0;
      float4 v = *(const float4*)&Wt[(size_t)(by + r) * 1024 + bx + c0];
      tile[r][c0] = v.x; tile[r][c0 + 1] = v.y;
      tile[r][c0 + 2] = v.z; tile[r][c0 + 3] = v.w;
    }
    __syncthreads();
#pragma unroll
    for (int p = 0; p < 4; ++p) {
      int r = p * 16 + r0;
      ushort4 o;
      o.x = f2bf(tile[c0 + 0][r]); o.y = f2bf(tile[c0 + 1][r]);
      o.z = f2bf(tile[c0 + 2][r]); o.w = f2bf(tile[c0 + 3][r]);
      *(ushort4*)&WtT[(size_t)(bx + r) * 1024 + by + c0] = o;
    }
  }
}

// ---- main: transposed token GEMM (C[h,t]) + fused relu-dot epilogue ----
// Tile 128h x 64t, grid (8 mh, 64 tt) = 512 blocks = 2/CU.
// Manual depth-2 pipeline: raw s_barrier + s_waitcnt vmcnt(3) (R3-proven).
__global__ __launch_bounds__(256) void main_kernel(
    const us* __restrict__ tokb, const us* __restrict__ WtT,
    const float* __restrict__ epart, const float* __restrict__ be,
    const float* __restrict__ bt, const float* __restrict__ wp,
    float* __restrict__ partial) {
  __shared__ __attribute__((aligned(16))) us Ws[2][4096];  // 128h x 32k per buf
  __shared__ __attribute__((aligned(16))) us Ts[2][2048];  // 64t x 32k per buf
  __shared__ __attribute__((aligned(16))) float eL[16][132];
  __shared__ __attribute__((aligned(16))) float btL[128];
  __shared__ __attribute__((aligned(16))) float wpL[128];
  __shared__ float pp[2][64][17];
  const int tid = threadIdx.x;
  const int mh = blockIdx.x, tt = blockIdx.y;
  const int h0 = mh << 7, b = tt >> 4, t0 = (tt & 15) << 6;
  // phase 1: entity act = sum of 8 k-partials + be -> eL; bt, wp -> LDS
#pragma unroll
  for (int p = 0; p < 2; ++p) {
    int q = (p << 8) + tid;
    int er = q >> 5, ec = (q & 31) << 2;
    f32x4 s = *(const f32x4*)&be[h0 + ec];
#pragma unroll
    for (int kc = 0; kc < 8; ++kc)
      s += *(const f32x4*)&epart[(((size_t)((kc << 6) + (b << 4) + er)) << 10) + h0 + ec];
    *(f32x4*)&eL[er][ec] = s;
  }
  if (tid < 128) btL[tid] = bt[h0 + tid];
  else wpL[tid - 128] = wp[h0 + tid - 128];
  asm volatile("" ::: "memory");
  // staging: per wave per tile, 3 DMA (Ws rows 16w.., rows 64+16w.., Ts rows 16w..)
  const int row1 = tid >> 2, kc4 = (tid & 3) << 3;
  const us* wP = WtT + (size_t)(h0 + row1) * 1024 + kc4;
  const us* tP = tokb + (size_t)((b << 10) + t0 + row1) * 1024 + kc4;
  const int w = tid >> 6;
  us* w0 = &Ws[0][w * 512]; us* w1 = &Ws[1][w * 512];
  us* t0L = &Ts[0][w * 512]; us* t1L = &Ts[1][w * 512];
  // prologue: tile0 -> buf0, tile1 -> buf1 (6 outstanding, 3/tile)
  gload_lds16(wP, w0); gload_lds16(wP + 65536, w0 + 2048);
  gload_lds16(tP, t0L);
  gload_lds16(wP + 32, w1); gload_lds16(wP + 65536 + 32, w1 + 2048);
  gload_lds16(tP + 32, t1L);
  const int lane = tid & 63, wm = (tid >> 7) & 1, wn = (tid >> 6) & 1;
  const int l16 = lane & 15, oct = lane >> 4, ko = oct << 3;
  int wfo[4], tfo[2];
#pragma unroll
  for (int i = 0; i < 4; ++i) wfo[i] = (((wm << 6) + (i << 4) + l16) << 5) + ko;
#pragma unroll
  for (int j = 0; j < 2; ++j) tfo[j] = (((wn << 5) + (j << 4) + l16) << 5) + ko;
  f32x4 acc[4][2] = {};
  for (int kt = 0; kt < 32; ++kt) {
    const us* Wb = Ws[kt & 1];
    const us* Tb = Ts[kt & 1];
    __builtin_amdgcn_s_waitcnt(0x0f73);  // vmcnt(3): oldest tile landed
    __builtin_amdgcn_s_barrier();
    asm volatile("" ::: "memory");
    short8 af[4], bfr[2];
#pragma unroll
    for (int i = 0; i < 4; ++i) af[i] = *(const short8*)&Wb[wfo[i]];
#pragma unroll
    for (int j = 0; j < 2; ++j) bfr[j] = *(const short8*)&Tb[tfo[j]];
#pragma unroll
    for (int i = 0; i < 4; ++i)
#pragma unroll
      for (int j = 0; j < 2; ++j)
        acc[i][j] = __builtin_amdgcn_mfma_f32_16x16x32_bf16(af[i], bfr[j], acc[i][j], 0, 0, 0);
    asm volatile("" ::: "memory");
    __builtin_amdgcn_s_barrier();
    // prefetch tile kt+2 into buf kt&1 (clamped dummy for last two iters)
    int nk = kt + 2; if (nk > 31) nk = 30;
    int ko2 = nk << 5;
    us* dw = (kt & 1) ? w1 : w0;
    us* dt = (kt & 1) ? t1L : t0L;
    gload_lds16(wP + ko2, dw); gload_lds16(wP + 65536 + ko2, dw + 2048);
    gload_lds16(tP + ko2, dt);
  }
  // ---- fused epilogue: per e, p[t] = sum_h relu(acc + bt + e) * Wp ----
  f32x4 btq[4], wpq[4];
#pragma unroll
  for (int i = 0; i < 4; ++i) {
    int hb = (wm << 6) + (i << 4) + (oct << 2);
    btq[i] = *(const f32x4*)&btL[hb];
    wpq[i] = *(const f32x4*)&wpL[hb];
  }
#pragma unroll
  for (int i = 0; i < 4; ++i)
#pragma unroll
    for (int j = 0; j < 2; ++j) acc[i][j] += btq[i];
#pragma unroll
  for (int e = 0; e < 16; ++e) {
    f32x4 ev[4];
#pragma unroll
    for (int i = 0; i < 4; ++i)
      ev[i] = *(const f32x4*)&eL[e][(wm << 6) + (i << 4) + (oct << 2)];
    float pj[2] = {0.f, 0.f};
#pragma unroll
    for (int j = 0; j < 2; ++j)
#pragma unroll
      for (int i = 0; i < 4; ++i)
#pragma unroll
        for (int r = 0; r < 4; ++r)
          pj[j] = fmaf(fmaxf(acc[i][j][r] + ev[i][r], 0.f), wpq[i][r], pj[j]);
#pragma unroll
    for (int j = 0; j < 2; ++j) {
      pj[j] += __shfl_xor(pj[j], 16, 64);
      pj[j] += __shfl_xor(pj[j], 32, 64);
    }
    if (oct == 0) {
#pragma unroll
      for (int j = 0; j < 2; ++j) pp[wm][(wn << 5) + (j << 4) + l16][e] = pj[j];
    }
  }
  __syncthreads();
#pragma unroll
  for (int q = 0; q < 4; ++q) {
    int flat = (q << 8) + tid;          // 0..1023 = e*64 + tl
    int e = flat >> 6, tl = flat & 63;
    float v = pp[0][tl][e] + pp[1][tl][e];
    partial[((size_t)mh << 16) + (size_t)((((b << 4) + e) << 10) + t0 + tl)] = v;
  }
}

// ---- finalize: sum 8 h-tile partials + bp, mask, sigmoid ----
__global__ __launch_bounds__(256) void finalize_kernel(
    const float* __restrict__ partial, const float* __restrict__ bp,
    const int* __restrict__ mask, float* __restrict__ out) {
  int idx = blockIdx.x * 256 + threadIdx.x;  // (b*16+e)*1024 + t
  float s = 0.f;
#pragma unroll
  for (int mh = 0; mh < 8; ++mh) s += partial[((size_t)mh << 16) + idx];
  float cls = s + bp[0];
  int b = idx >> 14, t = idx & 1023;
  if (mask[(b << 10) + t] == 0) cls = -10000.0f;
  float p = 1.0f / (1.0f + __expf(-cls));
  out[idx] = cls;
  out[65536 + idx] = p;
}

extern "C" void kernel_launch(void* const* d_in, const int* in_sizes, int n_in,
                              void* d_out, int out_size, void* d_ws, size_t ws_size,
                              hipStream_t stream) {
  const float* token = (const float*)d_in[0];
  const float* entity = (const float*)d_in[1];
  const int* mask = (const int*)d_in[2];
  const float* Wt = (const float*)d_in[3];
  const float* bt = (const float*)d_in[4];
  const float* We = (const float*)d_in[5];
  const float* be = (const float*)d_in[6];
  const float* Wp = (const float*)d_in[7];
  const float* bp = (const float*)d_in[8];
  float* out = (float*)d_out;

  char* ws = (char*)d_ws;
  us* tokb = (us*)ws;                                   // 8 MB
  us* WtT = tokb + (size_t)4096 * 1024;                 // 2 MB
  float* epart = (float*)(WtT + (size_t)1024 * 1024);   // 2 MB [8][64][1024]
  float* partial = epart + (size_t)8 * 64 * 1024;       // 2 MB [8][4*16*1024]

  prep_kernel<<<4608, 256, 0, stream>>>(token, tokb, Wt, WtT, entity, We, epart);
  main_kernel<<<dim3(8, 64), 256, 0, stream>>>(tokb, WtT, epart, be, bt, Wp, partial);
  finalize_kernel<<<256, 256, 0, stream>>>(partial, bp, mask, out);
}